// Round 7
// baseline (185.625 us; speedup 1.0000x reference)
//
#include <hip/hip_runtime.h>
#include <hip/hip_bf16.h>
#include <hip/hip_fp16.h>

#define FEAT 2048
#define NCLS 751
#define NPAD 768
#define NPRB 64
#define NGAL 256
#define WSCALE 256.0f

typedef _Float16 f16x8 __attribute__((ext_vector_type(8)));
typedef float f32x4 __attribute__((ext_vector_type(4)));

__device__ __forceinline__ unsigned short f2h_u(float x) {
  union { _Float16 h; unsigned short u; } v;
  v.h = (_Float16)x;
  return v.u;
}

// ---------------------------------------------------------------------------
// Kernel 1: per-feature moments -> BN scale s[f], shift t[f].
// 256 blocks x (8 features x 32 row-lanes).
// mean[f] = M2p - 2 M1p M1g + M2g ; E[d^2] = M4p - 4M3p M1g + 6M2p M2g - 4M1p M3g + M4g
// ---------------------------------------------------------------------------
__global__ __launch_bounds__(256)
void stats_kernel(const float* __restrict__ P, const float* __restrict__ G,
                  const float* __restrict__ gamma, const float* __restrict__ beta,
                  float* __restrict__ st) {
  const int t = threadIdx.x;
  const int fx = t & 7, ry = t >> 3;          // 8 features x 32 row-lanes
  const int f = blockIdx.x * 8 + fx;
  float a1 = 0, a2 = 0, a3 = 0, a4 = 0;
#pragma unroll
  for (int r = ry; r < NPRB; r += 32) {       // 2 iters
    float x = P[r * FEAT + f], x2 = x * x;
    a1 += x; a2 += x2; a3 += x2 * x; a4 += x2 * x2;
  }
  float b1 = 0, b2 = 0, b3 = 0, b4 = 0;
#pragma unroll
  for (int r = ry; r < NGAL; r += 32) {       // 8 iters
    float x = G[r * FEAT + f], x2 = x * x;
    b1 += x; b2 += x2; b3 += x2 * x; b4 += x2 * x2;
  }
  __shared__ float red[8][32][8];   // [moment][ry][fx]
  __shared__ float red2[8][4][8];   // [moment][quarter][fx]
  float vals[8] = {a1, a2, a3, a4, b1, b2, b3, b4};
#pragma unroll
  for (int m = 0; m < 8; ++m) red[m][ry][fx] = vals[m];
  __syncthreads();
  {
    int m = t >> 5, q = (t >> 3) & 3, fx2 = t & 7;
    float s = 0.f;
#pragma unroll
    for (int r = 0; r < 8; ++r) s += red[m][q * 8 + r][fx2];
    red2[m][q][fx2] = s;
  }
  __syncthreads();
  if (t < 8) {
    float mm[8];
#pragma unroll
    for (int m = 0; m < 8; ++m)
      mm[m] = red2[m][0][t] + red2[m][1][t] + red2[m][2][t] + red2[m][3][t];
    float M1p = mm[0] * (1.f / NPRB), M2p = mm[1] * (1.f / NPRB);
    float M3p = mm[2] * (1.f / NPRB), M4p = mm[3] * (1.f / NPRB);
    float M1g = mm[4] * (1.f / NGAL), M2g = mm[5] * (1.f / NGAL);
    float M3g = mm[6] * (1.f / NGAL), M4g = mm[7] * (1.f / NGAL);
    float mean = M2p - 2.f * M1p * M1g + M2g;
    float Ed2 = M4p - 4.f * M3p * M1g + 6.f * M2p * M2g - 4.f * M1p * M3g + M4g;
    float var = Ed2 - mean * mean;
    int ff = blockIdx.x * 8 + t;
    float sv = gamma[ff] / sqrtf(var + 1e-5f);
    st[ff] = sv;
    st[FEAT + ff] = beta[ff] - mean * sv;  // t[f]
  }
}

// ---------------------------------------------------------------------------
// Kernel 2 (fused): per class c:
//   Wp[c,f] = W[c,f] * s[f] * WSCALE (f16), bp[c] = b[c] + sum_f t[f] W[c,f]
// ---------------------------------------------------------------------------
__global__ void prepw_kernel(const float* __restrict__ W, const float* __restrict__ b,
                             const float* __restrict__ st,
                             unsigned short* __restrict__ Wp, float* __restrict__ bp) {
  int c = blockIdx.x;
  int f = threadIdx.x * 8;
  float4 w0 = make_float4(0.f, 0.f, 0.f, 0.f), w1 = w0;
  if (c < NCLS) {
    const float4* wsrc = (const float4*)(W + (size_t)c * FEAT + f);
    w0 = wsrc[0]; w1 = wsrc[1];
  }
  const float4* s4 = (const float4*)(st + f);
  float4 s0 = s4[0], s1 = s4[1];
  const float4* t4 = (const float4*)(st + FEAT + f);
  float4 t0 = t4[0], t1 = t4[1];
  uint4 u;
  u.x = (unsigned int)f2h_u(w0.x * s0.x * WSCALE) | ((unsigned int)f2h_u(w0.y * s0.y * WSCALE) << 16);
  u.y = (unsigned int)f2h_u(w0.z * s0.z * WSCALE) | ((unsigned int)f2h_u(w0.w * s0.w * WSCALE) << 16);
  u.z = (unsigned int)f2h_u(w1.x * s1.x * WSCALE) | ((unsigned int)f2h_u(w1.y * s1.y * WSCALE) << 16);
  u.w = (unsigned int)f2h_u(w1.z * s1.z * WSCALE) | ((unsigned int)f2h_u(w1.w * s1.w * WSCALE) << 16);
  *(uint4*)(Wp + (size_t)c * FEAT + f) = u;
  float acc = t0.x * w0.x + t0.y * w0.y + t0.z * w0.z + t0.w * w0.w +
              t1.x * w1.x + t1.y * w1.y + t1.z * w1.z + t1.w * w1.w;
#pragma unroll
  for (int off = 32; off > 0; off >>= 1) acc += __shfl_down(acc, off, 64);
  __shared__ float r[4];
  int wave = threadIdx.x >> 6, lane = threadIdx.x & 63;
  if (lane == 0) r[wave] = acc;
  __syncthreads();
  if (threadIdx.x == 0) bp[c] = (c < NCLS ? b[c] : 0.f) + r[0] + r[1] + r[2] + r[3];
}

// ---------------------------------------------------------------------------
// Kernel 3 (fused GEMM, A-in-registers + triple-buffered B + counted vmcnt):
// out = BN((P-G)^2) @ W'^T + b'. M=16384, N=768, K=2048. Tile 128x192, BK=32,
// 512 threads (8 waves, 8x1 map: wave-tile 16x192, acc[12]).
// Grid 512 blocks = exactly 2 blk/CU; XCD-chunked decode.
//
// Round-6 lesson: the 2-phase barrier-lockstep structure is the wall (m233) -
// latency coverage tweaks (r4/r5/r6) all flat/regressed. Structural fix:
//  * A fragment is lane-local (8 consecutive k of one row) -> computed
//    DIRECTLY in regs from G (2 dwordx4/row) + P (broadcast). No A LDS, no
//    A-gen barrier phase, LDS traffic halved.
//  * B triple-buffered (3 x 12 KB); raw s_barrier + asm vmcnt(2): B(t+2)
//    stays in flight ACROSS the barrier (~1.5 iters to land; T4 pattern).
//    Per-wave FIFO verified: af-compute's compiler-wait vmcnt(2) drains
//    B(t+1)+G/P; barrier keeps exactly B(t+2) outstanding (waves>=4 have
//    1 glds -> vmcnt(2) trivially safe).
//  * Epilogue: stage acc -> LDS (reuse Bs), coalesced scalar out-writes
//    (float4 to out is unaligned: 751 odd) - kills write amplification.
// Swizzle (64B rows, verified r5, 0 conflicts): slot = chunk ^ ((row>>1)&3);
// staging source chunk (lane&3)^((lane>>3)&3); frag fslot = fk^((frow>>1)&3).
// ---------------------------------------------------------------------------
__global__ __launch_bounds__(512, 4)
void gemm_fused_kernel(const float* __restrict__ P, const float* __restrict__ G,
                       const unsigned short* __restrict__ Wp,
                       const float* __restrict__ bp, float* __restrict__ out) {
  __shared__ unsigned short Bs[3][192 * 32];  // 3 x 12 KB f16 W' tiles

  const int tid = threadIdx.x;
  const int lane = tid & 63, wave = tid >> 6;  // 8 waves
  // XCD-chunked bijective decode: XCD k gets contiguous idp in [k*64, k*64+64)
  // -> per-XCD working set = 1 Wp panel (768 KB) + G (2 MB) + P <= 4 MB L2.
  const int idp = (blockIdx.x & 7) * 64 + (blockIdx.x >> 3);
  const int ntile = idp >> 7, mtile = idp & 127;
  const int p = mtile >> 1;

  const int frow = lane & 15, fk = lane >> 4;
  const int fslot = fk ^ ((frow >> 1) & 3);

  // A-direct: this lane's G row / P row, k-chunk base fk*8 (8 consecutive f32)
  const float* gptr = G + (size_t)((mtile & 1) * 128 + wave * 16 + frow) * FEAT + fk * 8;
  const float* pptr = P + (size_t)p * FEAT + fk * 8;  // same addr across frow: broadcast

  // B staging (pre-swizzled source chunk): instr A all 8 waves (rows 0..127),
  // instr B waves 0-3 (rows 128..191).
  const int bch = (lane & 3) ^ ((lane >> 3) & 3);
  const unsigned short* wsrc =
      Wp + (size_t)(ntile * 192 + wave * 16 + (lane >> 2)) * FEAT + bch * 8;
  const unsigned short* wsrc2 = wsrc + (size_t)128 * FEAT;
  const int bdo = wave * 1024;          // dest byte offset, instr A
  const int bdo2 = 8192 + wave * 1024;  // dest byte offset, instr B

  unsigned short* bsA = (unsigned short*)Bs[0];  // read tile t
  unsigned short* bsB = (unsigned short*)Bs[1];  // tile t+1 (landed/landing)
  unsigned short* bsC = (unsigned short*)Bs[2];  // tile t+2 (in flight)

  // ---- prologue: B(0), G/P(0), B(1) (issue order fixes vmcnt FIFO) ----
  __builtin_amdgcn_global_load_lds(
      (const __attribute__((address_space(1))) void*)wsrc,
      (__attribute__((address_space(3))) void*)((char*)bsA + bdo), 16, 0, 0);
  if (wave < 4)
    __builtin_amdgcn_global_load_lds(
        (const __attribute__((address_space(1))) void*)wsrc2,
        (__attribute__((address_space(3))) void*)((char*)bsA + bdo2), 16, 0, 0);
  float4 gA = ((const float4*)gptr)[0], gB = ((const float4*)gptr)[1];
  float4 pA = ((const float4*)pptr)[0], pB = ((const float4*)pptr)[1];
  __builtin_amdgcn_global_load_lds(
      (const __attribute__((address_space(1))) void*)(wsrc + 32),
      (__attribute__((address_space(3))) void*)((char*)bsB + bdo), 16, 0, 0);
  if (wave < 4)
    __builtin_amdgcn_global_load_lds(
        (const __attribute__((address_space(1))) void*)(wsrc2 + 32),
        (__attribute__((address_space(3))) void*)((char*)bsB + bdo2), 16, 0, 0);

  f16x8 af;  // af(0): compiler's wait for gA..pB drains B(0) too
  {
    float d0 = pA.x - gA.x, d1 = pA.y - gA.y, d2 = pA.z - gA.z, d3 = pA.w - gA.w;
    float d4 = pB.x - gB.x, d5 = pB.y - gB.y, d6 = pB.z - gB.z, d7 = pB.w - gB.w;
    af[0] = (_Float16)(d0 * d0); af[1] = (_Float16)(d1 * d1);
    af[2] = (_Float16)(d2 * d2); af[3] = (_Float16)(d3 * d3);
    af[4] = (_Float16)(d4 * d4); af[5] = (_Float16)(d5 * d5);
    af[6] = (_Float16)(d6 * d6); af[7] = (_Float16)(d7 * d7);
  }
  asm volatile("s_waitcnt vmcnt(2)" ::: "memory");  // B(0) landed; B(1) flying
  __builtin_amdgcn_sched_barrier(0);
  __builtin_amdgcn_s_barrier();
  __builtin_amdgcn_sched_barrier(0);

  f32x4 acc[12];
#pragma unroll
  for (int i = 0; i < 12; ++i) acc[i] = (f32x4){0.f, 0.f, 0.f, 0.f};

  // ---- main loop: 64 K-steps, raw barrier + counted vmcnt ----
  for (int t = 0; t < 64; ++t) {
    const int k0 = t * 32;
    if (t < 63) {  // 1. G/P(t+1) -> regs (oldest of this iter's issues)
      const float* gn = gptr + k0 + 32;
      const float* pn = pptr + k0 + 32;
      gA = ((const float4*)gn)[0]; gB = ((const float4*)gn)[1];
      pA = ((const float4*)pn)[0]; pB = ((const float4*)pn)[1];
    }
    if (t < 62) {  // 2. B(t+2) -> bsC (stays in flight across the barrier)
      __builtin_amdgcn_global_load_lds(
          (const __attribute__((address_space(1))) void*)(wsrc + k0 + 64),
          (__attribute__((address_space(3))) void*)((char*)bsC + bdo), 16, 0, 0);
      if (wave < 4)
        __builtin_amdgcn_global_load_lds(
            (const __attribute__((address_space(1))) void*)(wsrc2 + k0 + 64),
            (__attribute__((address_space(3))) void*)((char*)bsC + bdo2), 16, 0, 0);
    }

    // 3. MFMA on bsA: 3 chunks of {4 ds_read_b128, 4 mfma}
    __builtin_amdgcn_s_setprio(1);
#pragma unroll
    for (int c = 0; c < 3; ++c) {
      f16x8 bf0 = *(const f16x8*)(bsA + ((c * 4 + 0) * 16 + frow) * 32 + fslot * 8);
      f16x8 bf1 = *(const f16x8*)(bsA + ((c * 4 + 1) * 16 + frow) * 32 + fslot * 8);
      f16x8 bf2 = *(const f16x8*)(bsA + ((c * 4 + 2) * 16 + frow) * 32 + fslot * 8);
      f16x8 bf3 = *(const f16x8*)(bsA + ((c * 4 + 3) * 16 + frow) * 32 + fslot * 8);
      acc[c * 4 + 0] = __builtin_amdgcn_mfma_f32_16x16x32_f16(af, bf0, acc[c * 4 + 0], 0, 0, 0);
      acc[c * 4 + 1] = __builtin_amdgcn_mfma_f32_16x16x32_f16(af, bf1, acc[c * 4 + 1], 0, 0, 0);
      acc[c * 4 + 2] = __builtin_amdgcn_mfma_f32_16x16x32_f16(af, bf2, acc[c * 4 + 2], 0, 0, 0);
      acc[c * 4 + 3] = __builtin_amdgcn_mfma_f32_16x16x32_f16(af, bf3, acc[c * 4 + 3], 0, 0, 0);
    }
    __builtin_amdgcn_s_setprio(0);

    // 4. af(t+1) in regs (compiler waits vmcnt(2): drains G/P(t+1) + B(t+1))
    if (t < 63) {
      float d0 = pA.x - gA.x, d1 = pA.y - gA.y, d2 = pA.z - gA.z, d3 = pA.w - gA.w;
      float d4 = pB.x - gB.x, d5 = pB.y - gB.y, d6 = pB.z - gB.z, d7 = pB.w - gB.w;
      af[0] = (_Float16)(d0 * d0); af[1] = (_Float16)(d1 * d1);
      af[2] = (_Float16)(d2 * d2); af[3] = (_Float16)(d3 * d3);
      af[4] = (_Float16)(d4 * d4); af[5] = (_Float16)(d5 * d5);
      af[6] = (_Float16)(d6 * d6); af[7] = (_Float16)(d7 * d7);
    }

    // 5. barrier; only B(t+2) (<=2 loads) stays outstanding
    asm volatile("s_waitcnt vmcnt(2)" ::: "memory");
    __builtin_amdgcn_sched_barrier(0);
    __builtin_amdgcn_s_barrier();
    __builtin_amdgcn_sched_barrier(0);

    unsigned short* tmp = bsA; bsA = bsB; bsB = bsC; bsC = tmp;
  }

  // ---- epilogue: stage to LDS (reuse Bs), coalesced scalar writes ----
  // acc layout: row_in_wavetile = (lane>>4)*4 + r, col = ni*16 + (lane&15).
  float* sf = (float*)Bs;          // 32 x 196 f32 = 25088 B <= 36864
  const int LW = 196;              // padded stride: (196 mod 32 = 4) kills
                                   // the row-aliasing on staging writes
#pragma unroll 1
  for (int c = 0; c < 4; ++c) {    // chunk c = waves 2c, 2c+1 (32 rows)
    __syncthreads();
    if ((wave >> 1) == c) {
      const int lr0 = (wave & 1) * 16 + ((lane >> 4) << 2);
      const int lc = lane & 15;
#pragma unroll
      for (int ni = 0; ni < 12; ++ni)
#pragma unroll
        for (int r = 0; r < 4; ++r)
          sf[(lr0 + r) * LW + ni * 16 + lc] = acc[ni][r] * (1.0f / WSCALE);
    }
    __syncthreads();
    const int grow0 = mtile * 128 + c * 32;
#pragma unroll
    for (int i = 0; i < 12; ++i) {  // 32*192 / 512 = 12 iters, lane-contiguous
      int u = tid + i * 512;
      int row = u / 192, cin = u - row * 192;
      int col = ntile * 192 + cin;
      if (col < NCLS)
        out[(size_t)(grow0 + row) * NCLS + col] = sf[row * LW + cin] + bp[col];
    }
  }
}

// ---------------------------------------------------------------------------
extern "C" void kernel_launch(void* const* d_in, const int* in_sizes, int n_in,
                              void* d_out, int out_size, void* d_ws, size_t ws_size,
                              hipStream_t stream) {
  const float* P = (const float*)d_in[0];
  const float* G = (const float*)d_in[1];
  const float* gamma = (const float*)d_in[2];
  const float* beta = (const float*)d_in[3];
  const float* W = (const float*)d_in[4];
  const float* b = (const float*)d_in[5];
  float* out = (float*)d_out;

  float* st = (float*)d_ws;                           // s[2048], t[2048]
  float* bp = st + 2 * FEAT;                          // b'[768]
  unsigned short* Wp = (unsigned short*)(bp + NPAD);  // f16 W' [768, 2048]

  hipLaunchKernelGGL(stats_kernel, dim3(256), dim3(256), 0, stream, P, G, gamma, beta, st);
  hipLaunchKernelGGL(prepw_kernel, dim3(NPAD), dim3(256), 0, stream, W, b, st, Wp, bp);
  hipLaunchKernelGGL(gemm_fused_kernel, dim3(512), dim3(512), 0, stream, P, G, Wp, bp, out);
}